// Round 5
// baseline (450.683 us; speedup 1.0000x reference)
//
#include <hip/hip_runtime.h>

#define KCODES 1024
#define DDIM 128
#define HW 64
#define NPIX (32 * HW * HW)         // 131072 pixels
#define PLANE (HW * HW)             // 4096
#define BSTRIDE (DDIM * PLANE)      // 524288 floats per batch image
#define MARGIN 6e-5f
#define CAP_A 65536
#define CAP_B 8192
// margin budget: numpy fp32 band <=3.2e-5 + phase1 split-bf16 err <=5e-6
//              + resolve fp64 err ~1e-13 -> 6e-5 has ~45% headroom.

typedef __attribute__((ext_vector_type(8))) short bf16x8;   // MFMA A/B frag
typedef __attribute__((ext_vector_type(4))) float f32x4;    // MFMA C/D frag
typedef __attribute__((ext_vector_type(8))) unsigned short u16x8;

__device__ inline unsigned short f2bf(float f) {            // RNE fp32->bf16
    unsigned u = __builtin_bit_cast(unsigned, f);
    unsigned r = u + 0x7FFFu + ((u >> 16) & 1u);
    return (unsigned short)(r >> 16);
}
__device__ inline float bf2f(unsigned short h) {
    unsigned u = ((unsigned)h) << 16;
    return __builtin_bit_cast(float, u);
}

// ---------------------------------------------------------------------------
// prep (fused): all 16384 threads split the codebook into bf16 hi/lo in MFMA
// B-frag order (16B vector stores); threads t<1024 additionally compute
// Bsum[t] = numpy-pairwise sum of cb[t,:]^2 (fp32, contract off, f32x4 loads).
// ---------------------------------------------------------------------------
__global__ __launch_bounds__(256) void prep_kernel(const float* __restrict__ cb,
                                                   float* __restrict__ Bsum,
                                                   unsigned short* __restrict__ bs) {
    int t = blockIdx.x * 256 + threadIdx.x;   // 16384 threads
    {   // ---- split part: frag offset = ((c*4+s)*2+hl)*512 + l*8 + j
        int c = t >> 8, s = (t >> 6) & 3, l = t & 63;
        int n = l & 15, q = l >> 4;
        int k = c * 16 + n;
        int d0 = s * 32 + q * 8;
        const float* row = cb + k * DDIM + d0;
        f32x4 f0 = *(const f32x4*)(row);
        f32x4 f1 = *(const f32x4*)(row + 4);
        u16x8 hv, lv;
#pragma unroll
        for (int e = 0; e < 4; ++e) {
            float a = f0[e];
            unsigned short hb = f2bf(a);
            hv[e] = hb; lv[e] = f2bf(a - bf2f(hb));
            float b2 = f1[e];
            unsigned short hb2 = f2bf(b2);
            hv[4 + e] = hb2; lv[4 + e] = f2bf(b2 - bf2f(hb2));
        }
        int fh = ((c * 4 + s) * 2 + 0) * 512 + l * 8;
        int fl = ((c * 4 + s) * 2 + 1) * 512 + l * 8;
        *(u16x8*)(bs + fh) = hv;              // 16B aligned stores
        *(u16x8*)(bs + fl) = lv;
    }
    if (t < KCODES) {                         // ---- Bsum part
#pragma clang fp contract(off)
        const float* row = cb + t * DDIM;
        f32x4 u0 = *(const f32x4*)(row);
        f32x4 v0 = *(const f32x4*)(row + 4);
        float r0 = u0[0]*u0[0], r1 = u0[1]*u0[1], r2 = u0[2]*u0[2], r3 = u0[3]*u0[3];
        float r4 = v0[0]*v0[0], r5 = v0[1]*v0[1], r6 = v0[2]*v0[2], r7 = v0[3]*v0[3];
#pragma unroll
        for (int i = 1; i < 16; ++i) {
            f32x4 u = *(const f32x4*)(row + i * 8);
            f32x4 v = *(const f32x4*)(row + i * 8 + 4);
            r0 += u[0]*u[0]; r1 += u[1]*u[1]; r2 += u[2]*u[2]; r3 += u[3]*u[3];
            r4 += v[0]*v[0]; r5 += v[1]*v[1]; r6 += v[2]*v[2]; r7 += v[3]*v[3];
        }
        Bsum[t] = ((r0+r1)+(r2+r3)) + ((r4+r5)+(r6+r7));
    }
}

// ---------------------------------------------------------------------------
// phase1 v2: wg = 4 waves = 128 pixels (two h-rows); each wave owns 32 pixels
// as TWO 16-pixel A-tiles, so every B fragment read from LDS feeds 2x MFMA.
// A frags (-2z split bf16) loaded DIRECT from global (no z staging -> no
// bank conflicts, one barrier fewer; tile pair = full 128B lines).
// acc init = Bsum[k] -> MFMA output IS the distance. Top-3 tracking per row.
// ---------------------------------------------------------------------------
__global__ __launch_bounds__(256, 3) void phase1_mfma(
    const float* __restrict__ z, const float* __restrict__ cb,
    const unsigned short* __restrict__ bs, const float* __restrict__ Bsum,
    float* __restrict__ out, int* __restrict__ cntA, int2* __restrict__ listA,
    int* __restrict__ cntB, int* __restrict__ listB)
{
    __shared__ __align__(16) unsigned short bbuf[16384];  // 32KB B-group
    __shared__ int idxb[128];
    const int tid = threadIdx.x, lane = tid & 63, wv = tid >> 6;
    const int wg = blockIdx.x;                // 0..1023
    const int b = wg >> 5;
    const int h = (wg & 31) * 2 + (wv >> 1);
    const int w0 = (wv & 1) * 32;
    const int n = lane & 15, q = lane >> 4;
    const float* zb = z + (size_t)b * BSTRIDE + h * HW + w0;

    // A fragments: [t*4+s], A[m=n][k=q*8+j] = -2*z[d=s*32+q*8+j][w0+t*16+n]
    bf16x8 a_hi[8], a_lo[8];
#pragma unroll
    for (int t2 = 0; t2 < 2; ++t2)
#pragma unroll
    for (int s = 0; s < 4; ++s) {
        bf16x8 hi, lo;
#pragma unroll
        for (int j = 0; j < 8; ++j) {
            float a = -2.0f * zb[(size_t)(s * 32 + q * 8 + j) * PLANE + t2 * 16 + n];
            unsigned short hb = f2bf(a);
            hi[j] = (short)hb; lo[j] = (short)f2bf(a - bf2f(hb));
        }
        a_hi[t2 * 4 + s] = hi; a_lo[t2 * 4 + s] = lo;
    }

    // top-3 state per tile, vector component r = C/D row (pixel q*4+r)
    f32x4 m1a = 3.4e38f, m2a = 3.4e38f, m3a = 3.4e38f;
    f32x4 m1b = 3.4e38f, m2b = 3.4e38f, m3b = 3.4e38f;
    int i1a[4] = {0,0,0,0}, i2a[4] = {0,0,0,0};
    int i1b[4] = {0,0,0,0}, i2b[4] = {0,0,0,0};

    const f32x4* gsrc = (const f32x4*)bs;
    f32x4* ldst = (f32x4*)bbuf;
    const bf16x8* bfr = (const bf16x8*)bbuf;

    for (int g = 0; g < 16; ++g) {
        __syncthreads();                      // prior group's reads done
#pragma unroll
        for (int i = 0; i < 8; ++i)           // 32KB group copy (coalesced)
            ldst[i * 256 + tid] = gsrc[g * 2048 + i * 256 + tid];
        __syncthreads();
#pragma unroll
        for (int cc = 0; cc < 4; ++cc) {
            int kcol = (g * 4 + cc) * 16 + n;
            float bsv = Bsum[kcol];
            f32x4 acc0 = { bsv, bsv, bsv, bsv };
            f32x4 acc1 = acc0;
#pragma unroll
            for (int s = 0; s < 4; ++s) {
                bf16x8 bh = bfr[(cc * 8 + s * 2) * 64 + lane];
                bf16x8 bl = bfr[(cc * 8 + s * 2 + 1) * 64 + lane];
                acc0 = __builtin_amdgcn_mfma_f32_16x16x32_bf16(a_hi[s], bh, acc0, 0, 0, 0);
                acc1 = __builtin_amdgcn_mfma_f32_16x16x32_bf16(a_hi[4 + s], bh, acc1, 0, 0, 0);
                acc0 = __builtin_amdgcn_mfma_f32_16x16x32_bf16(a_lo[s], bh, acc0, 0, 0, 0);
                acc1 = __builtin_amdgcn_mfma_f32_16x16x32_bf16(a_lo[4 + s], bh, acc1, 0, 0, 0);
                acc0 = __builtin_amdgcn_mfma_f32_16x16x32_bf16(a_hi[s], bl, acc0, 0, 0, 0);
                acc1 = __builtin_amdgcn_mfma_f32_16x16x32_bf16(a_hi[4 + s], bl, acc1, 0, 0, 0);
            }
#define TRACK(ACC, M1, M2, M3, I1, I2) \
            _Pragma("unroll") \
            for (int r = 0; r < 4; ++r) { \
                float dv = ACC[r]; \
                bool lt1 = dv < M1[r]; \
                bool lt2 = dv < M2[r]; \
                M3[r] = lt2 ? M2[r] : fminf(M3[r], dv); \
                M2[r] = lt1 ? M1[r] : (lt2 ? dv : M2[r]); \
                I2[r] = lt1 ? I1[r] : (lt2 ? kcol : I2[r]); \
                M1[r] = lt1 ? dv : M1[r]; \
                I1[r] = lt1 ? kcol : I1[r]; \
            }
            TRACK(acc0, m1a, m2a, m3a, i1a, i2a)
            TRACK(acc1, m1b, m2b, m3b, i1b, i2b)
#undef TRACK
        }
    }

    // merge sorted-3 tuples across the 16 lanes sharing each row
#define MERGE(M1, M2, M3, I1, I2) \
        { \
            float b1 = __shfl_xor(M1[r], mask, 64); \
            float b2 = __shfl_xor(M2[r], mask, 64); \
            float b3 = __shfl_xor(M3[r], mask, 64); \
            int  ib1 = __shfl_xor(I1[r], mask, 64); \
            int  ib2 = __shfl_xor(I2[r], mask, 64); \
            float a1 = M1[r], a2 = M2[r], a3 = M3[r]; \
            int  ia1 = I1[r], ia2 = I2[r]; \
            bool bfirst = (b1 < a1) || (b1 == a1 && ib1 < ia1); \
            float x1 = bfirst ? b1 : a1;  int xi1 = bfirst ? ib1 : ia1; \
            float x2 = bfirst ? b2 : a2;  int xi2 = bfirst ? ib2 : ia2; \
            float x3 = bfirst ? b3 : a3; \
            float y1 = bfirst ? a1 : b1;  int yi1 = bfirst ? ia1 : ib1; \
            float y2 = bfirst ? a2 : b2; \
            bool ys = (y1 < x2) || (y1 == x2 && yi1 < xi2); \
            M1[r] = x1; I1[r] = xi1; \
            M2[r] = ys ? y1 : x2;  I2[r] = ys ? yi1 : xi2; \
            M3[r] = ys ? fminf(x2, y2) : fminf(x3, y1); \
        }
#pragma unroll
    for (int mask = 1; mask <= 8; mask <<= 1) {
#pragma unroll
        for (int r = 0; r < 4; ++r) {
            MERGE(m1a, m2a, m3a, i1a, i2a)
            MERGE(m1b, m2b, m3b, i1b, i2b)
        }
    }
#undef MERGE

    // within-wave idx exchange (idxb region disjoint per wave; DS in-order)
    if (n == 0) {
#pragma unroll
        for (int r = 0; r < 4; ++r) {
            idxb[wv * 32 + q * 4 + r]      = i1a[r];
            idxb[wv * 32 + 16 + q * 4 + r] = i1b[r];
        }
    }

    if (n == 0) {                    // ambiguity records (rare)
#pragma unroll
        for (int t2 = 0; t2 < 2; ++t2) {
#pragma unroll
            for (int r = 0; r < 4; ++r) {
                float g1 = t2 ? m1b[r] : m1a[r];
                float g2 = t2 ? m2b[r] : m2a[r];
                float g3 = t2 ? m3b[r] : m3a[r];
                int   k1 = t2 ? i1b[r] : i1a[r];
                int   k2 = t2 ? i2b[r] : i2a[r];
                if (g2 - g1 <= MARGIN) {
                    int pix = ((b * HW + h) * HW) + w0 + t2 * 16 + q * 4 + r;
                    int pos = atomicAdd(cntA, 1);
                    if (pos < CAP_A) {
                        int2 rec; rec.x = pix; rec.y = k1 | (k2 << 16);
                        listA[pos] = rec;
                    }
                    if (g3 - g1 <= MARGIN) {
                        int pb = atomicAdd(cntB, 1);
                        if (pb < CAP_B) listB[pb] = pix;
                    }
                }
            }
        }
    }

    // write guess: lane -> (pixel = t*16+n, d = dd*16 + q*4 + e)
#pragma unroll
    for (int t2 = 0; t2 < 2; ++t2) {
        int widx = idxb[wv * 32 + t2 * 16 + n];
        const float* crow = cb + (size_t)widx * DDIM;
        float* ob = out + (size_t)b * BSTRIDE + h * HW + w0 + t2 * 16 + n;
#pragma unroll
        for (int dd = 0; dd < 8; ++dd) {
            f32x4 c4 = *(const f32x4*)(crow + dd * 16 + q * 4);
            ob[(size_t)(dd * 16 + q * 4 + 0) * PLANE] = c4[0];
            ob[(size_t)(dd * 16 + q * 4 + 1) * PLANE] = c4[1];
            ob[(size_t)(dd * 16 + q * 4 + 2) * PLANE] = c4[2];
            ob[(size_t)(dd * 16 + q * 4 + 3) * PLANE] = c4[3];
        }
    }
}

// ---------------------------------------------------------------------------
// phase3a: resolve 2-candidate ambiguous pixels. One wave per item.
//   A    = numpy-pairwise sum of z^2 (fp32, contract off)
//   p    = dot in fp64 (lane-split + shuffle reduce; order-agnostic, err~1e-13)
//   D_k  = fl32( fl32(A + Bsum_k) - fl32(2*p) );  winner = lex min (D, k)
// No __syncthreads in the item loop (waves diverge); within-wave LDS in-order.
// ---------------------------------------------------------------------------
__global__ __launch_bounds__(256, 4) void phase3a_kernel(
    const float* __restrict__ z, const float* __restrict__ cb,
    const float* __restrict__ Bsum, float* __restrict__ out,
    const int* __restrict__ cntA, const int2* __restrict__ listA)
{
    __shared__ float zsh[4][128];
    const int tid = threadIdx.x, lane = tid & 63, wv = tid >> 6;
    int gwave = (blockIdx.x * 256 + tid) >> 6;
    int nwaves = gridDim.x * 4;
    int nitems = *cntA; if (nitems > CAP_A) nitems = CAP_A;

    for (int item = gwave; item < nitems; item += nwaves) {
        int2 rec = listA[item];
        int pix = rec.x;
        int k1 = rec.y & 0xFFFF, k2 = rec.y >> 16;
        int b = pix >> 12, h = (pix >> 6) & 63, w = pix & 63;
        const float* zp = z + (size_t)b * BSTRIDE + h * HW + w;

        float za = zp[(size_t)lane * PLANE];
        float zb = zp[(size_t)(lane + 64) * PLANE];
        zsh[wv][lane] = za;
        zsh[wv][lane + 64] = zb;

        float Apair;
        {
#pragma clang fp contract(off)
            const float* zr = zsh[wv];
            float r0,r1,r2,r3,r4,r5,r6,r7;
            r0 = zr[0]*zr[0]; r1 = zr[1]*zr[1]; r2 = zr[2]*zr[2]; r3 = zr[3]*zr[3];
            r4 = zr[4]*zr[4]; r5 = zr[5]*zr[5]; r6 = zr[6]*zr[6]; r7 = zr[7]*zr[7];
#pragma unroll
            for (int i = 8; i < DDIM; i += 8) {
                r0 += zr[i+0]*zr[i+0]; r1 += zr[i+1]*zr[i+1];
                r2 += zr[i+2]*zr[i+2]; r3 += zr[i+3]*zr[i+3];
                r4 += zr[i+4]*zr[i+4]; r5 += zr[i+5]*zr[i+5];
                r6 += zr[i+6]*zr[i+6]; r7 += zr[i+7]*zr[i+7];
            }
            Apair = ((r0+r1)+(r2+r3)) + ((r4+r5)+(r6+r7));
        }

        const float* c1 = cb + (size_t)k1 * DDIM;
        const float* c2 = cb + (size_t)k2 * DDIM;
        double p1 = fma((double)za, (double)c1[lane],
                        (double)zb * (double)c1[lane + 64]);
        double p2 = fma((double)za, (double)c2[lane],
                        (double)zb * (double)c2[lane + 64]);
        for (int off = 32; off; off >>= 1) {
            p1 += __shfl_xor(p1, off, 64);
            p2 += __shfl_xor(p2, off, 64);
        }
        float u1 = (float)(2.0 * p1), u2 = (float)(2.0 * p2);
        float D1, D2;
        {
#pragma clang fp contract(off)
            float t1 = Apair + Bsum[k1];
            float t2 = Apair + Bsum[k2];
            D1 = t1 - u1; D2 = t2 - u2;
        }
        int wk = (D1 < D2 || (D1 == D2 && k1 < k2)) ? k1 : k2;

        const float* cw = cb + (size_t)wk * DDIM;
        float* op = out + (size_t)b * BSTRIDE + h * HW + w;
        op[(size_t)lane * PLANE] = cw[lane];
        op[(size_t)(lane + 64) * PLANE] = cw[lane + 64];
    }
}

// ---------------------------------------------------------------------------
// phase3b: full-scan numpy-exact resolve for >=3-candidate pixels (rare).
// One block per item. Runs AFTER phase3a so its writes win.
// ---------------------------------------------------------------------------
__global__ __launch_bounds__(256, 2) void phase3b_kernel(
    const float* __restrict__ z, const float* __restrict__ cb,
    const float* __restrict__ Bsum, float* __restrict__ out,
    const int* __restrict__ cntB, const int* __restrict__ listB)
{
    __shared__ float zr[128];
    __shared__ float sD[256];
    __shared__ int   sK[256];
    const int tid = threadIdx.x;
    int nitems = *cntB; if (nitems > CAP_B) nitems = CAP_B;

    for (int item = blockIdx.x; item < nitems; item += gridDim.x) {
        int pix = listB[item];
        int b = pix >> 12, h = (pix >> 6) & 63, w = pix & 63;
        const float* zp = z + (size_t)b * BSTRIDE + h * HW + w;
        __syncthreads();                       // zr reuse guard
        if (tid < 128) zr[tid] = zp[(size_t)tid * PLANE];
        __syncthreads();

        float s0v, s1v, s2v, s3v;
#define SDOT(OUT, J) { int k = tid * 4 + (J); const float* c = cb + (size_t)k * DDIM; \
        float a0=0.f,a1=0.f,a2=0.f,a3=0.f; \
        for (int i = 0; i < DDIM; i += 4) { \
            a0 = __builtin_fmaf(zr[i+0], c[i+0], a0); \
            a1 = __builtin_fmaf(zr[i+1], c[i+1], a1); \
            a2 = __builtin_fmaf(zr[i+2], c[i+2], a2); \
            a3 = __builtin_fmaf(zr[i+3], c[i+3], a3); } \
        OUT = Bsum[k] - 2.0f * ((a0+a1)+(a2+a3)); }
        SDOT(s0v, 0) SDOT(s1v, 1) SDOT(s2v, 2) SDOT(s3v, 3)
#undef SDOT
        float lmin = fminf(fminf(s0v, s1v), fminf(s2v, s3v));
        sD[tid] = lmin; __syncthreads();
        for (int st = 128; st; st >>= 1) {
            if (tid < st) sD[tid] = fminf(sD[tid], sD[tid + st]);
            __syncthreads();
        }
        float smin = sD[0];
        __syncthreads();

        float Apair;
        {
#pragma clang fp contract(off)
            float r0,r1,r2,r3,r4,r5,r6,r7;
            r0 = zr[0]*zr[0]; r1 = zr[1]*zr[1]; r2 = zr[2]*zr[2]; r3 = zr[3]*zr[3];
            r4 = zr[4]*zr[4]; r5 = zr[5]*zr[5]; r6 = zr[6]*zr[6]; r7 = zr[7]*zr[7];
#pragma unroll
            for (int i = 8; i < DDIM; i += 8) {
                r0 += zr[i+0]*zr[i+0]; r1 += zr[i+1]*zr[i+1];
                r2 += zr[i+2]*zr[i+2]; r3 += zr[i+3]*zr[i+3];
                r4 += zr[i+4]*zr[i+4]; r5 += zr[i+5]*zr[i+5];
                r6 += zr[i+6]*zr[i+6]; r7 += zr[i+7]*zr[i+7];
            }
            Apair = ((r0+r1)+(r2+r3)) + ((r4+r5)+(r6+r7));
        }

        float bd = 3.4e38f; int bk = 1 << 30;
#define CAND(SV, J) { if (SV <= smin + MARGIN) { \
        int k = tid * 4 + (J); const float* c = cb + (size_t)k * DDIM; \
        double dacc = 0.0; \
        for (int i = 0; i < DDIM; ++i) dacc = fma((double)zr[i], (double)c[i], dacc); \
        float u = (float)(2.0 * dacc); \
        float tA = Apair + Bsum[k]; \
        float Dk = tA - u; \
        if (Dk < bd || (Dk == bd && k < bk)) { bd = Dk; bk = k; } } }
        CAND(s0v, 0) CAND(s1v, 1) CAND(s2v, 2) CAND(s3v, 3)
#undef CAND
        sD[tid] = bd; sK[tid] = bk; __syncthreads();
        for (int st = 128; st; st >>= 1) {
            if (tid < st) {
                float od = sD[tid + st]; int ok = sK[tid + st];
                if (od < sD[tid] || (od == sD[tid] && ok < sK[tid])) {
                    sD[tid] = od; sK[tid] = ok;
                }
            }
            __syncthreads();
        }
        int wk = sK[0];
        if (tid < 128)
            out[(size_t)b * BSTRIDE + (size_t)tid * PLANE + h * HW + w] =
                cb[(size_t)wk * DDIM + tid];
    }
}

// ---------------------------------------------------------------------------
extern "C" void kernel_launch(void* const* d_in, const int* in_sizes, int n_in,
                              void* d_out, int out_size, void* d_ws, size_t ws_size,
                              hipStream_t stream) {
    const float* z  = (const float*)d_in[0];
    const float* cb = (const float*)d_in[1];
    float* out = (float*)d_out;

    // ws: Bsum 4K | cnts 4K | bsplit 512K | listA 512K (int2) | listB 32K
    float* Bsum = (float*)d_ws;
    int* cntA = (int*)((char*)d_ws + 4096);
    int* cntB = cntA + 1;
    unsigned short* bsplit = (unsigned short*)((char*)d_ws + 8192);
    int2* listA = (int2*)((char*)d_ws + 8192 + 524288);
    int* listB  = (int*)((char*)d_ws + 8192 + 524288 + 524288);

    hipMemsetAsync(cntA, 0, 2 * sizeof(int), stream);
    prep_kernel<<<64, 256, 0, stream>>>(cb, Bsum, bsplit);
    phase1_mfma<<<NPIX / 128, 256, 0, stream>>>(z, cb, bsplit, Bsum, out,
                                                cntA, listA, cntB, listB);
    phase3a_kernel<<<1024, 256, 0, stream>>>(z, cb, Bsum, out, cntA, listA);
    phase3b_kernel<<<64, 256, 0, stream>>>(z, cb, Bsum, out, cntB, listB);
}